// Round 3
// baseline (274.188 us; speedup 1.0000x reference)
//
#include <hip/hip_runtime.h>
#include <limits.h>

#define S_U 256
#define N_IMP 128
#define OUT_STRIDE (4 + N_IMP)
#define TRUNC 0.015625f   // 2/512*4
#define WPB 4             // waves (= rays in flight) per 256-thread block
#define INV127 (1.0f / 127.0f)
#define MAX_BLOCKS 2048   // 8 blocks/CU x 256 CU -> fully resident, persistent waves

// ---------------- DPP cross-lane helpers (no LDS/ds_bpermute) ----------------
template<int CTRL, int RM, int BM>
__device__ __forceinline__ int dpp_i(int old_, int x) {
    return __builtin_amdgcn_update_dpp(old_, x, CTRL, RM, BM, false);
}
template<int CTRL, int RM, int BM>
__device__ __forceinline__ float dpp_f(float old_, float x) {
    return __int_as_float(__builtin_amdgcn_update_dpp(
        __float_as_int(old_), __float_as_int(x), CTRL, RM, BM, false));
}
__device__ __forceinline__ float readlane_f(float x, int l) {
    return __int_as_float(__builtin_amdgcn_readlane(__float_as_int(x), l));
}

// Full-wave inclusive scans (lane63 ends with the total).
__device__ __forceinline__ float wscan_add(float x) {
    x += dpp_f<0x111,0xf,0xf>(0.0f, x);
    x += dpp_f<0x112,0xf,0xf>(0.0f, x);
    x += dpp_f<0x114,0xf,0xf>(0.0f, x);
    x += dpp_f<0x118,0xf,0xf>(0.0f, x);
    x += dpp_f<0x142,0xa,0xf>(0.0f, x);
    x += dpp_f<0x143,0xc,0xf>(0.0f, x);
    return x;
}
__device__ __forceinline__ float wscan_mul(float x) {
    x *= dpp_f<0x111,0xf,0xf>(1.0f, x);
    x *= dpp_f<0x112,0xf,0xf>(1.0f, x);
    x *= dpp_f<0x114,0xf,0xf>(1.0f, x);
    x *= dpp_f<0x118,0xf,0xf>(1.0f, x);
    x *= dpp_f<0x142,0xa,0xf>(1.0f, x);
    x *= dpp_f<0x143,0xc,0xf>(1.0f, x);
    return x;
}
__device__ __forceinline__ int wscan_max(int x) {   // values >= 0
    x = max(x, dpp_i<0x111,0xf,0xf>(0, x));
    x = max(x, dpp_i<0x112,0xf,0xf>(0, x));
    x = max(x, dpp_i<0x114,0xf,0xf>(0, x));
    x = max(x, dpp_i<0x118,0xf,0xf>(0, x));
    x = max(x, dpp_i<0x142,0xa,0xf>(0, x));
    x = max(x, dpp_i<0x143,0xc,0xf>(0, x));
    return x;
}
__device__ __forceinline__ int wred_min(int x) {    // result valid in lane 63
    x = min(x, dpp_i<0x111,0xf,0xf>(INT_MAX, x));
    x = min(x, dpp_i<0x112,0xf,0xf>(INT_MAX, x));
    x = min(x, dpp_i<0x114,0xf,0xf>(INT_MAX, x));
    x = min(x, dpp_i<0x118,0xf,0xf>(INT_MAX, x));
    x = min(x, dpp_i<0x142,0xa,0xf>(INT_MAX, x));
    x = min(x, dpp_i<0x143,0xc,0xf>(INT_MAX, x));
    return x;
}

// Exact jmin = min{ j in [0,128] : (float)j * INV127 >= c }  (128 == "no sample")
__device__ __forceinline__ int jm_of(float c) {
    int jm = (int)ceilf(c * 127.0f);
    jm = min(max(jm, 0), 128);
    if (jm > 0 && (float)(jm - 1) * INV127 >= c) jm--;
    else if (jm < 128 && (float)jm * INV127 < c) jm++;
    return jm;
}

__global__ __launch_bounds__(256, 8) void tsdf_render_kernel(
    const float* __restrict__ occ,
    const float* __restrict__ zvals,
    const float* __restrict__ sdf,
    const float* __restrict__ rgbs,
    float* __restrict__ out,
    int n_rays)
{
    const int lane = threadIdx.x & 63;
    const int wv   = threadIdx.x >> 6;
    const int rstride = gridDim.x * WPB;          // rays advanced per iteration
    int ray = blockIdx.x * WPB + wv;

    __shared__ __align__(16) float s_cdf [WPB][S_U];
    __shared__ __align__(16) float s_zmid[WPB][S_U];
    __shared__ __align__(16) int   s_bs  [WPB][N_IMP];

    if (ray >= n_rays) return;                    // wave-uniform

    // prologue: latency-critical loads for the first ray
    float4 o4 = ((const float4*)(occ   + (size_t)ray * S_U))[lane];
    float4 z4 = ((const float4*)(zvals + (size_t)ray * S_U))[lane];

    for (;;) {
        // current-ray tail loads: consumed ~800+ cyc into this iteration -> self-hiding
        const float2 sd2 = ((const float2*)(sdf + (size_t)ray * N_IMP))[lane];
        const float2* rg = (const float2*)(rgbs + (size_t)ray * (N_IMP * 3)) + lane * 3;
        const float2 p0 = rg[0];   // r0 g0
        const float2 p1 = rg[1];   // b0 r1
        const float2 p2 = rg[2];   // g1 b1

        // next-ray head loads: issued now, consumed next iteration -> latency hidden
        const int nray = ray + rstride;
        const bool more = nray < n_rays;          // wave-uniform
        float4 o4n, z4n;
        if (more) {
            o4n = ((const float4*)(occ   + (size_t)nray * S_U))[lane];
            z4n = ((const float4*)(zvals + (size_t)nray * S_U))[lane];
        }

        // ---------------- coarse occupancy -> weights -----------------------
        float a0 = 1.0f / (1.0f + __expf(-10.0f * o4.x));
        float a1 = 1.0f / (1.0f + __expf(-10.0f * o4.y));
        float a2 = 1.0f / (1.0f + __expf(-10.0f * o4.z));
        float a3 = 1.0f / (1.0f + __expf(-10.0f * o4.w));
        float t0 = 1.0f - a0 + 1e-10f;
        float t1 = 1.0f - a1 + 1e-10f;
        float t2 = 1.0f - a2 + 1e-10f;
        float t3 = 1.0f - a3 + 1e-10f;

        float pp0 = t0, pp1 = pp0 * t1, pp2 = pp1 * t2, pp3 = pp2 * t3;
        float P = wscan_mul(pp3);
        float pbase = dpp_f<0x138,0xf,0xf>(1.0f, P);   // wave_shr1, lane0 = 1

        float w0 = a0 * pbase;
        float w1 = a1 * pbase * pp0;
        float w2 = a2 * pbase * pp1;
        float w3 = a3 * pbase * pp2;

        // ---------------- CDF over w_u[1..254] + 1e-5 -----------------------
        float v0 = (lane > 0)  ? w0 + 1e-5f : 0.0f;
        float v1 = w1 + 1e-5f;
        float v2 = w2 + 1e-5f;
        float v3 = (lane < 63) ? w3 + 1e-5f : 0.0f;
        float s0 = v0, s1 = s0 + v1, s2 = s1 + v2, s3 = s2 + v3;
        float S  = wscan_add(s3);
        float sbase = dpp_f<0x138,0xf,0xf>(0.0f, S);
        float total = readlane_f(S, 63);
        float invt = 1.0f / total;                     // exact (feeds bin decisions)

        float4 cdf4;
        cdf4.x = (sbase + s0) * invt;
        cdf4.y = (sbase + s1) * invt;
        cdf4.z = (sbase + s2) * invt;
        cdf4.w = (sbase + s3) * invt;

        float znext = dpp_f<0x130,0xf,0xf>(z4.x, z4.x); // wave_shl1
        float4 zm4;
        zm4.x = 0.5f * (z4.x + z4.y);
        zm4.y = 0.5f * (z4.y + z4.z);
        zm4.z = 0.5f * (z4.z + z4.w);
        zm4.w = 0.5f * (z4.w + znext);

        __builtin_amdgcn_wave_barrier();   // fence prev iteration's LDS gathers
        *((float4*)&s_cdf [wv][lane * 4]) = cdf4;
        *((float4*)&s_zmid[wv][lane * 4]) = zm4;
        *((int2*)&s_bs[wv][lane * 2]) = make_int2(0, 0);
        __builtin_amdgcn_wave_barrier();   // writes before scatter

        // ---------------- analytic CDF inversion ----------------------------
        int jm0 = jm_of(cdf4.x);
        int jm1 = jm_of(cdf4.y);
        int jm2 = jm_of(cdf4.z);
        int jm3 = jm_of(cdf4.w);
        if (lane == 63) jm3 = 128;
        int jmn = dpp_i<0x130,0xf,0xf>(128, jm0);

        int ib = lane * 4;
        if (jm0 < jm1) s_bs[wv][jm0] = ib;
        if (jm1 < jm2) s_bs[wv][jm1] = ib + 1;
        if (jm2 < jm3) s_bs[wv][jm2] = ib + 2;
        if (jm3 < jmn) s_bs[wv][jm3] = ib + 3;
        __builtin_amdgcn_wave_barrier();   // scatter before fill-read

        int2 bse = *((const int2*)&s_bs[wv][lane * 2]);
        int H  = wscan_max(max(bse.x, bse.y));
        int Hp = dpp_i<0x138,0xf,0xf>(0, H);
        int b0 = max(Hp, bse.x);
        int b1 = H;

        // ---------------- gather + interpolate ------------------------------
        const float* cdfp = s_cdf[wv];
        const float* zmp  = s_zmid[wv];
        float u0 = (float)(2 * lane)     * INV127;
        float u1 = (float)(2 * lane + 1) * INV127;

        float cb0 = cdfp[b0], ca0 = cdfp[b0 + 1];
        float zb0 = zmp[b0],  za0 = zmp[b0 + 1];
        float cb1 = cdfp[b1], ca1 = cdfp[b1 + 1];
        float zb1 = zmp[b1],  za1 = zmp[b1 + 1];

        float d0 = ca0 - cb0; d0 = (d0 < 1e-5f) ? 1.0f : d0;
        float d1 = ca1 - cb1; d1 = (d1 < 1e-5f) ? 1.0f : d1;
        float tt0 = (u0 - cb0) * __builtin_amdgcn_rcpf(d0);
        float tt1 = (u1 - cb1) * __builtin_amdgcn_rcpf(d1);
        float zs0 = zb0 + tt0 * (za0 - zb0);
        float zs1 = zb1 + tt1 * (za1 - zb1);

        // ---------------- first zero-crossing of sdf ------------------------
        float sn = dpp_f<0x130,0xf,0xf>(sd2.x, sd2.x);
        int c = INT_MAX;
        if (sd2.x * sd2.y < 0.0f)                  c = 2 * lane;
        else if (lane < 63 && sd2.y * sn < 0.0f)   c = 2 * lane + 1;
        c = wred_min(c);
        int cis = __builtin_amdgcn_readlane(c, 63);
        cis = (cis == INT_MAX) ? 0 : cis;
        float zca = readlane_f(zs0, cis >> 1);
        float zcb = readlane_f(zs1, cis >> 1);
        float z_min = (cis & 1) ? zcb : zca;

        // ---------------- TSDF alpha + truncation mask ----------------------
        float x0 = sd2.x * (1.0f / TRUNC);
        float x1 = sd2.y * (1.0f / TRUNC);
        float al0 = __builtin_amdgcn_rcpf(2.0f + __expf(x0) + __expf(-x0));
        float al1 = __builtin_amdgcn_rcpf(2.0f + __expf(x1) + __expf(-x1));
        float zlim = z_min + TRUNC;
        if (!(zs0 < zlim)) al0 = 0.0f;
        if (!(zs1 < zlim)) al1 = 0.0f;

        float At = wscan_add(al0 + al1);
        float asum = readlane_f(At, 63);
        float inv_s = __builtin_amdgcn_rcpf(asum + 1e-8f);
        float g0 = al0 * inv_s;
        float g1 = al1 * inv_s;

        // ---------------- composite (lane63 holds the totals) ---------------
        float rr = wscan_add(g0 * p0.x + g1 * p1.y);
        float gg = wscan_add(g0 * p0.y + g1 * p2.x);
        float bb = wscan_add(g0 * p1.x + g1 * p2.y);
        float dd = wscan_add(g0 * zs0  + g1 * zs1);

        float* ob = out + (size_t)ray * OUT_STRIDE;
        ((float2*)(ob + 4))[lane] = make_float2(g0, g1);
        if (lane == 63) {
            ob[0] = fminf(fmaxf(rr, 0.0f), 1.0f);
            ob[1] = fminf(fmaxf(gg, 0.0f), 1.0f);
            ob[2] = fminf(fmaxf(bb, 0.0f), 1.0f);
            ob[3] = dd;
        }

        if (!more) break;
        o4 = o4n; z4 = z4n; ray = nray;
    }
}

extern "C" void kernel_launch(void* const* d_in, const int* in_sizes, int n_in,
                              void* d_out, int out_size, void* d_ws, size_t ws_size,
                              hipStream_t stream) {
    const float* occ  = (const float*)d_in[0];
    const float* z    = (const float*)d_in[1];
    const float* sdf  = (const float*)d_in[2];
    const float* rgbs = (const float*)d_in[3];
    float* out = (float*)d_out;
    const int n_rays = in_sizes[0] / S_U;
    int nblk = (n_rays + WPB - 1) / WPB;
    if (nblk > MAX_BLOCKS) nblk = MAX_BLOCKS;
    hipLaunchKernelGGL(tsdf_render_kernel, dim3(nblk), dim3(256), 0, stream,
                       occ, z, sdf, rgbs, out, n_rays);
}

// Round 4
// 269.577 us; speedup vs baseline: 1.0171x; 1.0171x over previous
//
#include <hip/hip_runtime.h>
#include <limits.h>

#define S_U 256
#define N_IMP 128
#define OUT_STRIDE (4 + N_IMP)
#define TRUNC 0.015625f   // 2/512*4
#define WPB 8             // waves (= rays) per 512-thread block: halves WG-dispatch count
#define INV127 (1.0f / 127.0f)

// ---------------- DPP cross-lane helpers (no LDS/ds_bpermute) ----------------
template<int CTRL, int RM, int BM>
__device__ __forceinline__ int dpp_i(int old_, int x) {
    return __builtin_amdgcn_update_dpp(old_, x, CTRL, RM, BM, false);
}
template<int CTRL, int RM, int BM>
__device__ __forceinline__ float dpp_f(float old_, float x) {
    return __int_as_float(__builtin_amdgcn_update_dpp(
        __float_as_int(old_), __float_as_int(x), CTRL, RM, BM, false));
}
__device__ __forceinline__ float readlane_f(float x, int l) {
    return __int_as_float(__builtin_amdgcn_readlane(__float_as_int(x), l));
}

// Full-wave inclusive scans (lane63 ends with the total).
// ctrl: 0x111..0x118 row_shr 1/2/4/8, 0x142 bcast15 (rows 1,3), 0x143 bcast31 (rows 2,3)
__device__ __forceinline__ float wscan_add(float x) {
    x += dpp_f<0x111,0xf,0xf>(0.0f, x);
    x += dpp_f<0x112,0xf,0xf>(0.0f, x);
    x += dpp_f<0x114,0xf,0xf>(0.0f, x);
    x += dpp_f<0x118,0xf,0xf>(0.0f, x);
    x += dpp_f<0x142,0xa,0xf>(0.0f, x);
    x += dpp_f<0x143,0xc,0xf>(0.0f, x);
    return x;
}
__device__ __forceinline__ float wscan_mul(float x) {
    x *= dpp_f<0x111,0xf,0xf>(1.0f, x);
    x *= dpp_f<0x112,0xf,0xf>(1.0f, x);
    x *= dpp_f<0x114,0xf,0xf>(1.0f, x);
    x *= dpp_f<0x118,0xf,0xf>(1.0f, x);
    x *= dpp_f<0x142,0xa,0xf>(1.0f, x);
    x *= dpp_f<0x143,0xc,0xf>(1.0f, x);
    return x;
}
__device__ __forceinline__ int wscan_max(int x) {   // values >= 0
    x = max(x, dpp_i<0x111,0xf,0xf>(0, x));
    x = max(x, dpp_i<0x112,0xf,0xf>(0, x));
    x = max(x, dpp_i<0x114,0xf,0xf>(0, x));
    x = max(x, dpp_i<0x118,0xf,0xf>(0, x));
    x = max(x, dpp_i<0x142,0xa,0xf>(0, x));
    x = max(x, dpp_i<0x143,0xc,0xf>(0, x));
    return x;
}
__device__ __forceinline__ int wred_min(int x) {    // result valid in lane 63
    x = min(x, dpp_i<0x111,0xf,0xf>(INT_MAX, x));
    x = min(x, dpp_i<0x112,0xf,0xf>(INT_MAX, x));
    x = min(x, dpp_i<0x114,0xf,0xf>(INT_MAX, x));
    x = min(x, dpp_i<0x118,0xf,0xf>(INT_MAX, x));
    x = min(x, dpp_i<0x142,0xa,0xf>(INT_MAX, x));
    x = min(x, dpp_i<0x143,0xc,0xf>(INT_MAX, x));
    return x;
}

// Exact jmin = min{ j in [0,128] : (float)j * INV127 >= c }  (128 == "no sample")
// Same predicate orientation as the original binary search -> bit-identical bins.
__device__ __forceinline__ int jm_of(float c) {
    int jm = (int)ceilf(c * 127.0f);
    jm = min(max(jm, 0), 128);
    if (jm > 0 && (float)(jm - 1) * INV127 >= c) jm--;
    else if (jm < 128 && (float)jm * INV127 < c) jm++;
    return jm;
}

__global__ __launch_bounds__(512) void tsdf_render_kernel(
    const float* __restrict__ occ,
    const float* __restrict__ zvals,
    const float* __restrict__ sdf,
    const float* __restrict__ rgbs,
    float* __restrict__ out)
{
    const int lane = threadIdx.x & 63;
    const int wv   = threadIdx.x >> 6;
    const int ray  = blockIdx.x * WPB + wv;

    __shared__ __align__(16) float s_cdf [WPB][S_U];
    __shared__ __align__(16) float s_zmid[WPB][S_U];
    __shared__ __align__(16) int   s_bs  [WPB][N_IMP];   // "below" segment starts

    // ---------------- global loads issued up front (latency overlap) --------
    const float4 o4  = ((const float4*)(occ   + (size_t)ray * S_U))[lane];
    const float4 z4  = ((const float4*)(zvals + (size_t)ray * S_U))[lane];
    const float2 sd2 = ((const float2*)(sdf   + (size_t)ray * N_IMP))[lane];
    const float2* rg = (const float2*)(rgbs + (size_t)ray * (N_IMP * 3)) + lane * 3;
    const float2 p0 = rg[0];   // r0 g0
    const float2 p1 = rg[1];   // b0 r1
    const float2 p2 = rg[2];   // g1 b1

    // ---------------- coarse occupancy -> weights ---------------------------
    // exact div kept: alphas feed the CDF (bin decisions)
    float a0 = 1.0f / (1.0f + __expf(-10.0f * o4.x));
    float a1 = 1.0f / (1.0f + __expf(-10.0f * o4.y));
    float a2 = 1.0f / (1.0f + __expf(-10.0f * o4.z));
    float a3 = 1.0f / (1.0f + __expf(-10.0f * o4.w));
    float t0 = 1.0f - a0 + 1e-10f;
    float t1 = 1.0f - a1 + 1e-10f;
    float t2 = 1.0f - a2 + 1e-10f;
    float t3 = 1.0f - a3 + 1e-10f;

    float pp0 = t0, pp1 = pp0 * t1, pp2 = pp1 * t2, pp3 = pp2 * t3;
    float P = wscan_mul(pp3);                       // inclusive product scan
    float pbase = dpp_f<0x138,0xf,0xf>(1.0f, P);    // wave_shr1: exclusive, lane0=1

    float w0 = a0 * pbase;
    float w1 = a1 * pbase * pp0;
    float w2 = a2 * pbase * pp1;
    float w3 = a3 * pbase * pp2;

    // ---------------- CDF over w_u[1..254] + 1e-5 ---------------------------
    float v0 = (lane > 0)  ? w0 + 1e-5f : 0.0f;
    float v1 = w1 + 1e-5f;
    float v2 = w2 + 1e-5f;
    float v3 = (lane < 63) ? w3 + 1e-5f : 0.0f;
    float s0 = v0, s1 = s0 + v1, s2 = s1 + v2, s3 = s2 + v3;
    float S  = wscan_add(s3);                       // inclusive sum scan
    float sbase = dpp_f<0x138,0xf,0xf>(0.0f, S);    // exclusive base
    float total = readlane_f(S, 63);
    float invt = 1.0f / total;                      // exact (feeds bin decisions)

    float4 cdf4;
    cdf4.x = (sbase + s0) * invt;
    cdf4.y = (sbase + s1) * invt;
    cdf4.z = (sbase + s2) * invt;
    cdf4.w = (sbase + s3) * invt;
    *((float4*)&s_cdf[wv][lane * 4]) = cdf4;

    float znext = dpp_f<0x130,0xf,0xf>(z4.x, z4.x); // wave_shl1 (shfl_down 1), lane63 -> own
    float4 zm4;
    zm4.x = 0.5f * (z4.x + z4.y);
    zm4.y = 0.5f * (z4.y + z4.z);
    zm4.z = 0.5f * (z4.z + z4.w);
    zm4.w = 0.5f * (z4.w + znext);                  // index 255: only hit in degenerate t~0 case
    *((float4*)&s_zmid[wv][lane * 4]) = zm4;

    // init segment-start array
    *((int2*)&s_bs[wv][lane * 2]) = make_int2(0, 0);

    __builtin_amdgcn_wave_barrier();   // LDS is in-order per wave; pin compiler order

    // ---------------- analytic CDF inversion (replaces binary search) ------
    int jm0 = jm_of(cdf4.x);
    int jm1 = jm_of(cdf4.y);
    int jm2 = jm_of(cdf4.z);
    int jm3 = jm_of(cdf4.w);
    if (lane == 63) jm3 = 128;                       // entry 255 doesn't exist; cap entry 254
    int jmn = dpp_i<0x130,0xf,0xf>(128, jm0);        // next lane's jm0, lane63 -> sentinel

    int ib = lane * 4;
    if (jm0 < jm1) s_bs[wv][jm0] = ib;
    if (jm1 < jm2) s_bs[wv][jm1] = ib + 1;
    if (jm2 < jm3) s_bs[wv][jm2] = ib + 2;
    if (jm3 < jmn) s_bs[wv][jm3] = ib + 3;

    __builtin_amdgcn_wave_barrier();

    // fill: below[j] = max segment-start index at position <= j  (DPP max-scan)
    int2 bse = *((const int2*)&s_bs[wv][lane * 2]);
    int H  = wscan_max(max(bse.x, bse.y));           // inclusive through sample 2*lane+1
    int Hp = dpp_i<0x138,0xf,0xf>(0, H);             // through sample 2*lane-1
    int b0 = max(Hp, bse.x);                         // below for sample 2*lane
    int b1 = H;                                      // below for sample 2*lane+1

    // ---------------- gather + interpolate (single-level LDS reads) ---------
    const float* cdfp = s_cdf[wv];
    const float* zmp  = s_zmid[wv];
    float u0 = (float)(2 * lane)     * INV127;
    float u1 = (float)(2 * lane + 1) * INV127;

    float cb0 = cdfp[b0], ca0 = cdfp[b0 + 1];
    float zb0 = zmp[b0],  za0 = zmp[b0 + 1];
    float cb1 = cdfp[b1], ca1 = cdfp[b1 + 1];
    float zb1 = zmp[b1],  za1 = zmp[b1 + 1];

    float d0 = ca0 - cb0; d0 = (d0 < 1e-5f) ? 1.0f : d0;
    float d1 = ca1 - cb1; d1 = (d1 < 1e-5f) ? 1.0f : d1;
    float tt0 = (u0 - cb0) * __builtin_amdgcn_rcpf(d0);   // rcp(1.0)==1.0 exactly
    float tt1 = (u1 - cb1) * __builtin_amdgcn_rcpf(d1);
    float zs0 = zb0 + tt0 * (za0 - zb0);
    float zs1 = zb1 + tt1 * (za1 - zb1);

    // ---------------- first zero-crossing of sdf ----------------------------
    float sn = dpp_f<0x130,0xf,0xf>(sd2.x, sd2.x);   // sdf[2*lane+2]; lane63 guarded
    int c = INT_MAX;
    if (sd2.x * sd2.y < 0.0f)                  c = 2 * lane;
    else if (lane < 63 && sd2.y * sn < 0.0f)   c = 2 * lane + 1;
    c = wred_min(c);
    int cis = __builtin_amdgcn_readlane(c, 63);
    cis = (cis == INT_MAX) ? 0 : cis;
    float zca = readlane_f(zs0, cis >> 1);
    float zcb = readlane_f(zs1, cis >> 1);
    float z_min = (cis & 1) ? zcb : zca;

    // ---------------- TSDF alpha + truncation mask --------------------------
    float x0 = sd2.x * (1.0f / TRUNC);
    float x1 = sd2.y * (1.0f / TRUNC);
    float al0 = __builtin_amdgcn_rcpf(2.0f + __expf(x0) + __expf(-x0));
    float al1 = __builtin_amdgcn_rcpf(2.0f + __expf(x1) + __expf(-x1));
    float zlim = z_min + TRUNC;
    if (!(zs0 < zlim)) al0 = 0.0f;
    if (!(zs1 < zlim)) al1 = 0.0f;

    float At = wscan_add(al0 + al1);
    float asum = readlane_f(At, 63);
    float inv_s = __builtin_amdgcn_rcpf(asum + 1e-8f);
    float g0 = al0 * inv_s;
    float g1 = al1 * inv_s;

    // ---------------- composite (lane63 holds the totals) -------------------
    float rr = wscan_add(g0 * p0.x + g1 * p1.y);
    float gg = wscan_add(g0 * p0.y + g1 * p2.x);
    float bb = wscan_add(g0 * p1.x + g1 * p2.y);
    float dd = wscan_add(g0 * zs0  + g1 * zs1);

    float* ob = out + (size_t)ray * OUT_STRIDE;
    ((float2*)(ob + 4))[lane] = make_float2(g0, g1);
    if (lane == 63) {
        ob[0] = fminf(fmaxf(rr, 0.0f), 1.0f);
        ob[1] = fminf(fmaxf(gg, 0.0f), 1.0f);
        ob[2] = fminf(fmaxf(bb, 0.0f), 1.0f);
        ob[3] = dd;
    }
}

extern "C" void kernel_launch(void* const* d_in, const int* in_sizes, int n_in,
                              void* d_out, int out_size, void* d_ws, size_t ws_size,
                              hipStream_t stream) {
    const float* occ  = (const float*)d_in[0];
    const float* z    = (const float*)d_in[1];
    const float* sdf  = (const float*)d_in[2];
    const float* rgbs = (const float*)d_in[3];
    float* out = (float*)d_out;
    const int n_rays = in_sizes[0] / S_U;
    hipLaunchKernelGGL(tsdf_render_kernel, dim3(n_rays / WPB), dim3(512), 0, stream,
                       occ, z, sdf, rgbs, out);
}

// Round 5
// 268.927 us; speedup vs baseline: 1.0196x; 1.0024x over previous
//
#include <hip/hip_runtime.h>
#include <limits.h>

#define S_U 256
#define N_IMP 128
#define OUT_STRIDE (4 + N_IMP)
#define TRUNC 0.015625f   // 2/512*4
#define WPB 4             // waves per 256-thread block; each wave = 2 rays
#define RPB (WPB * 2)     // rays per block
#define INV127 (1.0f / 127.0f)

// ---------------- DPP cross-lane helpers (no LDS/ds_bpermute) ----------------
template<int CTRL, int RM, int BM>
__device__ __forceinline__ int dpp_i(int old_, int x) {
    return __builtin_amdgcn_update_dpp(old_, x, CTRL, RM, BM, false);
}
template<int CTRL, int RM, int BM>
__device__ __forceinline__ float dpp_f(float old_, float x) {
    return __int_as_float(__builtin_amdgcn_update_dpp(
        __float_as_int(old_), __float_as_int(x), CTRL, RM, BM, false));
}
__device__ __forceinline__ float readlane_f(float x, int l) {
    return __int_as_float(__builtin_amdgcn_readlane(__float_as_int(x), l));
}

// Full-wave inclusive scans (lane63 ends with the total).
__device__ __forceinline__ float wscan_add(float x) {
    x += dpp_f<0x111,0xf,0xf>(0.0f, x);
    x += dpp_f<0x112,0xf,0xf>(0.0f, x);
    x += dpp_f<0x114,0xf,0xf>(0.0f, x);
    x += dpp_f<0x118,0xf,0xf>(0.0f, x);
    x += dpp_f<0x142,0xa,0xf>(0.0f, x);
    x += dpp_f<0x143,0xc,0xf>(0.0f, x);
    return x;
}
__device__ __forceinline__ float wscan_mul(float x) {
    x *= dpp_f<0x111,0xf,0xf>(1.0f, x);
    x *= dpp_f<0x112,0xf,0xf>(1.0f, x);
    x *= dpp_f<0x114,0xf,0xf>(1.0f, x);
    x *= dpp_f<0x118,0xf,0xf>(1.0f, x);
    x *= dpp_f<0x142,0xa,0xf>(1.0f, x);
    x *= dpp_f<0x143,0xc,0xf>(1.0f, x);
    return x;
}
__device__ __forceinline__ int wscan_max(int x) {   // values >= 0
    x = max(x, dpp_i<0x111,0xf,0xf>(0, x));
    x = max(x, dpp_i<0x112,0xf,0xf>(0, x));
    x = max(x, dpp_i<0x114,0xf,0xf>(0, x));
    x = max(x, dpp_i<0x118,0xf,0xf>(0, x));
    x = max(x, dpp_i<0x142,0xa,0xf>(0, x));
    x = max(x, dpp_i<0x143,0xc,0xf>(0, x));
    return x;
}
__device__ __forceinline__ int wred_min(int x) {    // result valid in lane 63
    x = min(x, dpp_i<0x111,0xf,0xf>(INT_MAX, x));
    x = min(x, dpp_i<0x112,0xf,0xf>(INT_MAX, x));
    x = min(x, dpp_i<0x114,0xf,0xf>(INT_MAX, x));
    x = min(x, dpp_i<0x118,0xf,0xf>(INT_MAX, x));
    x = min(x, dpp_i<0x142,0xa,0xf>(INT_MAX, x));
    x = min(x, dpp_i<0x143,0xc,0xf>(INT_MAX, x));
    return x;
}

// Exact jmin = min{ j in [0,128] : (float)j * INV127 >= c }  (128 == "no sample")
__device__ __forceinline__ int jm_of(float c) {
    int jm = (int)ceilf(c * 127.0f);
    jm = min(max(jm, 0), 128);
    if (jm > 0 && (float)(jm - 1) * INV127 >= c) jm--;
    else if (jm < 128 && (float)jm * INV127 < c) jm++;
    return jm;
}

// coarse occupancy -> normalized cdf4 + zmid4 for one ray (pure per-wave math)
__device__ __forceinline__ void coarse_cdf(const float4 o4, const float4 z4,
                                           int lane, float4& cdf4, float4& zm4) {
    float a0 = 1.0f / (1.0f + __expf(-10.0f * o4.x));
    float a1 = 1.0f / (1.0f + __expf(-10.0f * o4.y));
    float a2 = 1.0f / (1.0f + __expf(-10.0f * o4.z));
    float a3 = 1.0f / (1.0f + __expf(-10.0f * o4.w));
    float t0 = 1.0f - a0 + 1e-10f;
    float t1 = 1.0f - a1 + 1e-10f;
    float t2 = 1.0f - a2 + 1e-10f;
    float t3 = 1.0f - a3 + 1e-10f;

    float pp0 = t0, pp1 = pp0 * t1, pp2 = pp1 * t2, pp3 = pp2 * t3;
    float P = wscan_mul(pp3);
    float pbase = dpp_f<0x138,0xf,0xf>(1.0f, P);    // wave_shr1: exclusive, lane0=1

    float w0 = a0 * pbase;
    float w1 = a1 * pbase * pp0;
    float w2 = a2 * pbase * pp1;
    float w3 = a3 * pbase * pp2;

    float v0 = (lane > 0)  ? w0 + 1e-5f : 0.0f;
    float v1 = w1 + 1e-5f;
    float v2 = w2 + 1e-5f;
    float v3 = (lane < 63) ? w3 + 1e-5f : 0.0f;
    float s0 = v0, s1 = s0 + v1, s2 = s1 + v2, s3 = s2 + v3;
    float S  = wscan_add(s3);
    float sbase = dpp_f<0x138,0xf,0xf>(0.0f, S);
    float total = readlane_f(S, 63);
    float invt = 1.0f / total;                      // exact (feeds bin decisions)

    cdf4.x = (sbase + s0) * invt;
    cdf4.y = (sbase + s1) * invt;
    cdf4.z = (sbase + s2) * invt;
    cdf4.w = (sbase + s3) * invt;

    float znext = dpp_f<0x130,0xf,0xf>(z4.x, z4.x); // wave_shl1
    zm4.x = 0.5f * (z4.x + z4.y);
    zm4.y = 0.5f * (z4.y + z4.z);
    zm4.z = 0.5f * (z4.z + z4.w);
    zm4.w = 0.5f * (z4.w + znext);
}

__global__ __launch_bounds__(256) void tsdf_render_kernel(
    const float* __restrict__ occ,
    const float* __restrict__ zvals,
    const float* __restrict__ sdf,
    const float* __restrict__ rgbs,
    float* __restrict__ out)
{
    const int lane = threadIdx.x & 63;
    const int wv   = threadIdx.x >> 6;
    const int rayA = blockIdx.x * RPB + wv * 2;
    const int rayB = rayA + 1;
    const int rA = wv * 2, rB = rA + 1;

    __shared__ __align__(16) float s_cdf [RPB][S_U];
    __shared__ __align__(16) float s_zmid[RPB][S_U];
    __shared__ __align__(16) int   s_bs  [RPB][N_IMP];

    // ---------------- phase-1 loads: both rays' coarse streams --------------
    const float4 o4A = ((const float4*)(occ   + (size_t)rayA * S_U))[lane];
    const float4 z4A = ((const float4*)(zvals + (size_t)rayA * S_U))[lane];
    const float4 o4B = ((const float4*)(occ   + (size_t)rayB * S_U))[lane];
    const float4 z4B = ((const float4*)(zvals + (size_t)rayB * S_U))[lane];

    // ---------------- coarse -> cdf/zmid, both rays (independent chains) ----
    float4 cdf4A, zm4A, cdf4B, zm4B;
    coarse_cdf(o4A, z4A, lane, cdf4A, zm4A);
    coarse_cdf(o4B, z4B, lane, cdf4B, zm4B);

    // ---------------- phase-2 loads: importance streams (o4/z4 now dead) ----
    const float2 sd2A = ((const float2*)(sdf + (size_t)rayA * N_IMP))[lane];
    const float2 sd2B = ((const float2*)(sdf + (size_t)rayB * N_IMP))[lane];
    const float2* rgA = (const float2*)(rgbs + (size_t)rayA * (N_IMP * 3)) + lane * 3;
    const float2* rgB = (const float2*)(rgbs + (size_t)rayB * (N_IMP * 3)) + lane * 3;
    const float2 p0A = rgA[0], p1A = rgA[1], p2A = rgA[2];
    const float2 p0B = rgB[0], p1B = rgB[1], p2B = rgB[2];

    // ---------------- LDS stage ---------------------------------------------
    *((float4*)&s_cdf [rA][lane * 4]) = cdf4A;
    *((float4*)&s_zmid[rA][lane * 4]) = zm4A;
    *((float4*)&s_cdf [rB][lane * 4]) = cdf4B;
    *((float4*)&s_zmid[rB][lane * 4]) = zm4B;
    *((int2*)&s_bs[rA][lane * 2]) = make_int2(0, 0);
    *((int2*)&s_bs[rB][lane * 2]) = make_int2(0, 0);
    __builtin_amdgcn_wave_barrier();   // init before scatter

    // ---------------- analytic CDF inversion, both rays ---------------------
    {
        int jm0 = jm_of(cdf4A.x), jm1 = jm_of(cdf4A.y);
        int jm2 = jm_of(cdf4A.z), jm3 = jm_of(cdf4A.w);
        if (lane == 63) jm3 = 128;
        int jmn = dpp_i<0x130,0xf,0xf>(128, jm0);
        int ib = lane * 4;
        if (jm0 < jm1) s_bs[rA][jm0] = ib;
        if (jm1 < jm2) s_bs[rA][jm1] = ib + 1;
        if (jm2 < jm3) s_bs[rA][jm2] = ib + 2;
        if (jm3 < jmn) s_bs[rA][jm3] = ib + 3;
    }
    {
        int jm0 = jm_of(cdf4B.x), jm1 = jm_of(cdf4B.y);
        int jm2 = jm_of(cdf4B.z), jm3 = jm_of(cdf4B.w);
        if (lane == 63) jm3 = 128;
        int jmn = dpp_i<0x130,0xf,0xf>(128, jm0);
        int ib = lane * 4;
        if (jm0 < jm1) s_bs[rB][jm0] = ib;
        if (jm1 < jm2) s_bs[rB][jm1] = ib + 1;
        if (jm2 < jm3) s_bs[rB][jm2] = ib + 2;
        if (jm3 < jmn) s_bs[rB][jm3] = ib + 3;
    }
    __builtin_amdgcn_wave_barrier();   // scatter before fill-read

    // ---------------- fill via DPP max-scan, both rays -----------------------
    int2 bseA = *((const int2*)&s_bs[rA][lane * 2]);
    int2 bseB = *((const int2*)&s_bs[rB][lane * 2]);
    int HA  = wscan_max(max(bseA.x, bseA.y));
    int HB  = wscan_max(max(bseB.x, bseB.y));
    int HpA = dpp_i<0x138,0xf,0xf>(0, HA);
    int HpB = dpp_i<0x138,0xf,0xf>(0, HB);
    int b0A = max(HpA, bseA.x), b1A = HA;
    int b0B = max(HpB, bseB.x), b1B = HB;

    // ---------------- gather + interpolate -----------------------------------
    float u0 = (float)(2 * lane)     * INV127;
    float u1 = (float)(2 * lane + 1) * INV127;

    const float* cdfpA = s_cdf[rA];
    const float* zmpA  = s_zmid[rA];
    float cb0A = cdfpA[b0A], ca0A = cdfpA[b0A + 1];
    float zb0A = zmpA[b0A],  za0A = zmpA[b0A + 1];
    float cb1A = cdfpA[b1A], ca1A = cdfpA[b1A + 1];
    float zb1A = zmpA[b1A],  za1A = zmpA[b1A + 1];

    const float* cdfpB = s_cdf[rB];
    const float* zmpB  = s_zmid[rB];
    float cb0B = cdfpB[b0B], ca0B = cdfpB[b0B + 1];
    float zb0B = zmpB[b0B],  za0B = zmpB[b0B + 1];
    float cb1B = cdfpB[b1B], ca1B = cdfpB[b1B + 1];
    float zb1B = zmpB[b1B],  za1B = zmpB[b1B + 1];

    float d0A = ca0A - cb0A; d0A = (d0A < 1e-5f) ? 1.0f : d0A;
    float d1A = ca1A - cb1A; d1A = (d1A < 1e-5f) ? 1.0f : d1A;
    float d0B = ca0B - cb0B; d0B = (d0B < 1e-5f) ? 1.0f : d0B;
    float d1B = ca1B - cb1B; d1B = (d1B < 1e-5f) ? 1.0f : d1B;
    float tt0A = (u0 - cb0A) * __builtin_amdgcn_rcpf(d0A);
    float tt1A = (u1 - cb1A) * __builtin_amdgcn_rcpf(d1A);
    float tt0B = (u0 - cb0B) * __builtin_amdgcn_rcpf(d0B);
    float tt1B = (u1 - cb1B) * __builtin_amdgcn_rcpf(d1B);
    float zs0A = zb0A + tt0A * (za0A - zb0A);
    float zs1A = zb1A + tt1A * (za1A - zb1A);
    float zs0B = zb0B + tt0B * (za0B - zb0B);
    float zs1B = zb1B + tt1B * (za1B - zb1B);

    // ---------------- first zero-crossing of sdf, both rays ------------------
    float snA = dpp_f<0x130,0xf,0xf>(sd2A.x, sd2A.x);
    float snB = dpp_f<0x130,0xf,0xf>(sd2B.x, sd2B.x);
    int cA = INT_MAX, cB = INT_MAX;
    if (sd2A.x * sd2A.y < 0.0f)                 cA = 2 * lane;
    else if (lane < 63 && sd2A.y * snA < 0.0f)  cA = 2 * lane + 1;
    if (sd2B.x * sd2B.y < 0.0f)                 cB = 2 * lane;
    else if (lane < 63 && sd2B.y * snB < 0.0f)  cB = 2 * lane + 1;
    cA = wred_min(cA);
    cB = wred_min(cB);
    int ciA = __builtin_amdgcn_readlane(cA, 63);
    int ciB = __builtin_amdgcn_readlane(cB, 63);
    ciA = (ciA == INT_MAX) ? 0 : ciA;
    ciB = (ciB == INT_MAX) ? 0 : ciB;
    float zcaA = readlane_f(zs0A, ciA >> 1);
    float zcbA = readlane_f(zs1A, ciA >> 1);
    float zcaB = readlane_f(zs0B, ciB >> 1);
    float zcbB = readlane_f(zs1B, ciB >> 1);
    float z_minA = (ciA & 1) ? zcbA : zcaA;
    float z_minB = (ciB & 1) ? zcbB : zcaB;

    // ---------------- TSDF alpha + truncation mask ---------------------------
    float x0A = sd2A.x * (1.0f / TRUNC), x1A = sd2A.y * (1.0f / TRUNC);
    float x0B = sd2B.x * (1.0f / TRUNC), x1B = sd2B.y * (1.0f / TRUNC);
    float al0A = __builtin_amdgcn_rcpf(2.0f + __expf(x0A) + __expf(-x0A));
    float al1A = __builtin_amdgcn_rcpf(2.0f + __expf(x1A) + __expf(-x1A));
    float al0B = __builtin_amdgcn_rcpf(2.0f + __expf(x0B) + __expf(-x0B));
    float al1B = __builtin_amdgcn_rcpf(2.0f + __expf(x1B) + __expf(-x1B));
    float zlimA = z_minA + TRUNC;
    float zlimB = z_minB + TRUNC;
    if (!(zs0A < zlimA)) al0A = 0.0f;
    if (!(zs1A < zlimA)) al1A = 0.0f;
    if (!(zs0B < zlimB)) al0B = 0.0f;
    if (!(zs1B < zlimB)) al1B = 0.0f;

    float AtA = wscan_add(al0A + al1A);
    float AtB = wscan_add(al0B + al1B);
    float inv_sA = __builtin_amdgcn_rcpf(readlane_f(AtA, 63) + 1e-8f);
    float inv_sB = __builtin_amdgcn_rcpf(readlane_f(AtB, 63) + 1e-8f);
    float g0A = al0A * inv_sA, g1A = al1A * inv_sA;
    float g0B = al0B * inv_sB, g1B = al1B * inv_sB;

    // ---------------- composite (lane63 holds totals) ------------------------
    float rrA = wscan_add(g0A * p0A.x + g1A * p1A.y);
    float ggA = wscan_add(g0A * p0A.y + g1A * p2A.x);
    float bbA = wscan_add(g0A * p1A.x + g1A * p2A.y);
    float ddA = wscan_add(g0A * zs0A  + g1A * zs1A);
    float rrB = wscan_add(g0B * p0B.x + g1B * p1B.y);
    float ggB = wscan_add(g0B * p0B.y + g1B * p2B.x);
    float bbB = wscan_add(g0B * p1B.x + g1B * p2B.y);
    float ddB = wscan_add(g0B * zs0B  + g1B * zs1B);

    float* obA = out + (size_t)rayA * OUT_STRIDE;
    float* obB = out + (size_t)rayB * OUT_STRIDE;
    ((float2*)(obA + 4))[lane] = make_float2(g0A, g1A);
    ((float2*)(obB + 4))[lane] = make_float2(g0B, g1B);
    if (lane == 63) {
        obA[0] = fminf(fmaxf(rrA, 0.0f), 1.0f);
        obA[1] = fminf(fmaxf(ggA, 0.0f), 1.0f);
        obA[2] = fminf(fmaxf(bbA, 0.0f), 1.0f);
        obA[3] = ddA;
        obB[0] = fminf(fmaxf(rrB, 0.0f), 1.0f);
        obB[1] = fminf(fmaxf(ggB, 0.0f), 1.0f);
        obB[2] = fminf(fmaxf(bbB, 0.0f), 1.0f);
        obB[3] = ddB;
    }
}

extern "C" void kernel_launch(void* const* d_in, const int* in_sizes, int n_in,
                              void* d_out, int out_size, void* d_ws, size_t ws_size,
                              hipStream_t stream) {
    const float* occ  = (const float*)d_in[0];
    const float* z    = (const float*)d_in[1];
    const float* sdf  = (const float*)d_in[2];
    const float* rgbs = (const float*)d_in[3];
    float* out = (float*)d_out;
    const int n_rays = in_sizes[0] / S_U;
    hipLaunchKernelGGL(tsdf_render_kernel, dim3(n_rays / RPB), dim3(256), 0, stream,
                       occ, z, sdf, rgbs, out);
}